// Round 1
// baseline (602.100 us; speedup 1.0000x reference)
//
#include <hip/hip_runtime.h>
#include <hip/hip_bf16.h>

// GAT forward: q/k/v/res projections + edge attention + softmax + aggregation.
// N=50000 nodes, E=800000 edges, IN_DIM=128, H=8 heads, D=16.

#define NEG_SLOPE 0.2f

// ---------------------------------------------------------------------------
// Kernel 1: 4 projections. Block computes 64 rows x 128 cols for each of the
// 4 weight matrices. h tile staged in LDS (padded to kill bank conflicts),
// W^T staged in 32-row chunks.
// ---------------------------------------------------------------------------
__global__ __launch_bounds__(256) void proj4_kernel(
    const float* __restrict__ h,
    const float* __restrict__ Wq, const float* __restrict__ Wk,
    const float* __restrict__ Wv, const float* __restrict__ Wres,
    float* __restrict__ q, float* __restrict__ k, float* __restrict__ v,
    float* __restrict__ res, int N)
{
    __shared__ float hs[64][129];   // +1 pad: conflict-free column reads
    __shared__ float wt[32][132];   // W^T chunk, padded (row stride 528B, 16B-aligned)

    const int tid = threadIdx.x;
    const int row0 = blockIdx.x * 64;

    // stage h tile: 64 rows x 128 floats
    for (int t = tid; t < 2048; t += 256) {
        int r = t >> 5, c4 = t & 31;
        int gr = row0 + r;
        float4 val = make_float4(0.f, 0.f, 0.f, 0.f);
        if (gr < N) val = reinterpret_cast<const float4*>(h)[(size_t)gr * 32 + c4];
        hs[r][c4 * 4 + 0] = val.x;
        hs[r][c4 * 4 + 1] = val.y;
        hs[r][c4 * 4 + 2] = val.z;
        hs[r][c4 * 4 + 3] = val.w;
    }

    const float* Ws[4] = {Wq, Wk, Wv, Wres};
    float*       Os[4] = {q, k, v, res};

    const int cg = tid & 15, rg = tid >> 4;
    const int c0 = cg * 8, r0 = rg * 4;

    for (int w = 0; w < 4; ++w) {
        const float* W = Ws[w];
        float acc[4][8];
        #pragma unroll
        for (int a = 0; a < 4; ++a)
            #pragma unroll
            for (int b = 0; b < 8; ++b) acc[a][b] = 0.f;

        for (int ic = 0; ic < 4; ++ic) {
            __syncthreads();
            // stage W^T chunk: wt[i][c] = W[c][ic*32 + i], i in [0,32)
            #pragma unroll
            for (int j = 0; j < 4; ++j) {
                int u = tid + 256 * j;          // 0..1023
                int c = u >> 3, i4 = u & 7;     // c in [0,128), i4 in [0,8)
                float4 val = reinterpret_cast<const float4*>(W)[c * 32 + ic * 8 + i4];
                wt[i4 * 4 + 0][c] = val.x;
                wt[i4 * 4 + 1][c] = val.y;
                wt[i4 * 4 + 2][c] = val.z;
                wt[i4 * 4 + 3][c] = val.w;
            }
            __syncthreads();
            #pragma unroll
            for (int i = 0; i < 32; ++i) {
                float4 wv0 = *reinterpret_cast<const float4*>(&wt[i][c0]);
                float4 wv1 = *reinterpret_cast<const float4*>(&wt[i][c0 + 4]);
                float wvv[8] = {wv0.x, wv0.y, wv0.z, wv0.w,
                                wv1.x, wv1.y, wv1.z, wv1.w};
                #pragma unroll
                for (int rr = 0; rr < 4; ++rr) {
                    float hv = hs[r0 + rr][ic * 32 + i];
                    #pragma unroll
                    for (int cc = 0; cc < 8; ++cc)
                        acc[rr][cc] = fmaf(hv, wvv[cc], acc[rr][cc]);
                }
            }
        }

        float* O = Os[w];
        #pragma unroll
        for (int rr = 0; rr < 4; ++rr) {
            int gr = row0 + r0 + rr;
            if (gr < N) {
                float4 o0 = make_float4(acc[rr][0], acc[rr][1], acc[rr][2], acc[rr][3]);
                float4 o1 = make_float4(acc[rr][4], acc[rr][5], acc[rr][6], acc[rr][7]);
                reinterpret_cast<float4*>(O)[(size_t)gr * 32 + (c0 >> 2) + 0] = o0;
                reinterpret_cast<float4*>(O)[(size_t)gr * 32 + (c0 >> 2) + 1] = o1;
            }
        }
    }
}

// ---------------------------------------------------------------------------
// Kernel 2: per-edge, per-head attention score.
// 8 lanes per edge (one per head). e = leakyrelu(dot16(q[dst,h], k[src,h]));
// ex = exp(e) stored; z[dst,h] += ex (softmax denominator; max-shift skipped,
// mathematically identical and exp fits fp32 comfortably here).
// ---------------------------------------------------------------------------
__global__ __launch_bounds__(256) void edge_score_kernel(
    const float* __restrict__ q, const float* __restrict__ k,
    const int* __restrict__ src, const int* __restrict__ dst,
    float* __restrict__ ex, float* __restrict__ z, int E)
{
    int t = blockIdx.x * 256 + threadIdx.x;
    int e = t >> 3;
    int hh = t & 7;
    if (e >= E) return;
    int s = src[e], d = dst[e];
    const float4* qr = reinterpret_cast<const float4*>(q + (size_t)d * 128 + hh * 16);
    const float4* kr = reinterpret_cast<const float4*>(k + (size_t)s * 128 + hh * 16);
    float acc = 0.f;
    #pragma unroll
    for (int j = 0; j < 4; ++j) {
        float4 a = qr[j];
        float4 b = kr[j];
        acc += a.x * b.x + a.y * b.y + a.z * b.z + a.w * b.w;
    }
    float ev = (acc >= 0.f) ? acc : NEG_SLOPE * acc;
    float exv = __expf(ev);
    ex[(size_t)e * 8 + hh] = exv;
    atomicAdd(&z[(size_t)d * 8 + hh], exv);
}

// ---------------------------------------------------------------------------
// Kernel 3: aggregation. 128 lanes per edge (one per output dim).
// rst[dst] += (ex/z[dst]) * v[src].  rst already holds the residual.
// ---------------------------------------------------------------------------
__global__ __launch_bounds__(256) void agg_kernel(
    const float* __restrict__ v, const float* __restrict__ ex,
    const float* __restrict__ z, const int* __restrict__ src,
    const int* __restrict__ dst, float* __restrict__ rst, int E)
{
    int t = blockIdx.x * 256 + threadIdx.x;
    int e = t >> 7;
    int dcol = t & 127;
    if (e >= E) return;
    int s = src[e], d = dst[e];
    int hh = dcol >> 4;
    float alpha = ex[(size_t)e * 8 + hh] / z[(size_t)d * 8 + hh];
    float val = alpha * v[(size_t)s * 128 + dcol];
    atomicAdd(&rst[(size_t)d * 128 + dcol], val);
}

extern "C" void kernel_launch(void* const* d_in, const int* in_sizes, int n_in,
                              void* d_out, int out_size, void* d_ws, size_t ws_size,
                              hipStream_t stream) {
    const float* h    = (const float*)d_in[0];
    // d_in[1] = edge_features (dead code in reference)
    const int*   src  = (const int*)d_in[2];
    const int*   dst  = (const int*)d_in[3];
    const float* Wq   = (const float*)d_in[4];
    const float* Wk   = (const float*)d_in[5];
    const float* Wv   = (const float*)d_in[6];
    // d_in[7] = We (dead code in reference)
    const float* Wres = (const float*)d_in[8];
    float* rst = (float*)d_out;

    const int N = in_sizes[0] / 128;   // 50000
    const int E = in_sizes[2];         // 800000

    float* q  = (float*)d_ws;
    float* k  = q  + (size_t)N * 128;
    float* v  = k  + (size_t)N * 128;
    float* ex = v  + (size_t)N * 128;
    float* z  = ex + (size_t)E * 8;

    hipMemsetAsync(z, 0, (size_t)N * 8 * sizeof(float), stream);

    proj4_kernel<<<(N + 63) / 64, 256, 0, stream>>>(h, Wq, Wk, Wv, Wres,
                                                    q, k, v, rst, N);
    edge_score_kernel<<<((size_t)E * 8 + 255) / 256, 256, 0, stream>>>(
        q, k, src, dst, ex, z, E);
    agg_kernel<<<((size_t)E * 128 + 255) / 256, 256, 0, stream>>>(
        v, ex, z, src, dst, rst, E);
}

// Round 2
// 486.621 us; speedup vs baseline: 1.2373x; 1.2373x over previous
//
#include <hip/hip_runtime.h>
#include <hip/hip_bf16.h>

// GAT forward, CSR-fused version.
// N=50000 nodes, E=800000 edges, IN_DIM=128, H=8 heads, D=16.
//
// Pipeline:
//   1. proj4: q,k,v into ws; residual h@Wres.T into d_out.
//   2. CSR build by dst: histogram -> 1-block scan -> scatter src into csr_src.
//   3. fused_agg: one wave per node; q[d] in regs; per edge: 8 head dots via
//      shfl_xor reduce, leaky+exp, accumulate ex*v and z in regs; divide once.

#define NEG_SLOPE 0.2f

// ---------------------------------------------------------------------------
// Kernel 1: 4 projections (unchanged from round 0).
// ---------------------------------------------------------------------------
__global__ __launch_bounds__(256) void proj4_kernel(
    const float* __restrict__ h,
    const float* __restrict__ Wq, const float* __restrict__ Wk,
    const float* __restrict__ Wv, const float* __restrict__ Wres,
    float* __restrict__ q, float* __restrict__ k, float* __restrict__ v,
    float* __restrict__ res, int N)
{
    __shared__ float hs[64][129];
    __shared__ float wt[32][132];

    const int tid = threadIdx.x;
    const int row0 = blockIdx.x * 64;

    for (int t = tid; t < 2048; t += 256) {
        int r = t >> 5, c4 = t & 31;
        int gr = row0 + r;
        float4 val = make_float4(0.f, 0.f, 0.f, 0.f);
        if (gr < N) val = reinterpret_cast<const float4*>(h)[(size_t)gr * 32 + c4];
        hs[r][c4 * 4 + 0] = val.x;
        hs[r][c4 * 4 + 1] = val.y;
        hs[r][c4 * 4 + 2] = val.z;
        hs[r][c4 * 4 + 3] = val.w;
    }

    const float* Ws[4] = {Wq, Wk, Wv, Wres};
    float*       Os[4] = {q, k, v, res};

    const int cg = tid & 15, rg = tid >> 4;
    const int c0 = cg * 8, r0 = rg * 4;

    for (int w = 0; w < 4; ++w) {
        const float* W = Ws[w];
        float acc[4][8];
        #pragma unroll
        for (int a = 0; a < 4; ++a)
            #pragma unroll
            for (int b = 0; b < 8; ++b) acc[a][b] = 0.f;

        for (int ic = 0; ic < 4; ++ic) {
            __syncthreads();
            #pragma unroll
            for (int j = 0; j < 4; ++j) {
                int u = tid + 256 * j;
                int c = u >> 3, i4 = u & 7;
                float4 val = reinterpret_cast<const float4*>(W)[c * 32 + ic * 8 + i4];
                wt[i4 * 4 + 0][c] = val.x;
                wt[i4 * 4 + 1][c] = val.y;
                wt[i4 * 4 + 2][c] = val.z;
                wt[i4 * 4 + 3][c] = val.w;
            }
            __syncthreads();
            #pragma unroll
            for (int i = 0; i < 32; ++i) {
                float4 wv0 = *reinterpret_cast<const float4*>(&wt[i][c0]);
                float4 wv1 = *reinterpret_cast<const float4*>(&wt[i][c0 + 4]);
                float wvv[8] = {wv0.x, wv0.y, wv0.z, wv0.w,
                                wv1.x, wv1.y, wv1.z, wv1.w};
                #pragma unroll
                for (int rr = 0; rr < 4; ++rr) {
                    float hv = hs[r0 + rr][ic * 32 + i];
                    #pragma unroll
                    for (int cc = 0; cc < 8; ++cc)
                        acc[rr][cc] = fmaf(hv, wvv[cc], acc[rr][cc]);
                }
            }
        }

        float* O = Os[w];
        #pragma unroll
        for (int rr = 0; rr < 4; ++rr) {
            int gr = row0 + r0 + rr;
            if (gr < N) {
                float4 o0 = make_float4(acc[rr][0], acc[rr][1], acc[rr][2], acc[rr][3]);
                float4 o1 = make_float4(acc[rr][4], acc[rr][5], acc[rr][6], acc[rr][7]);
                reinterpret_cast<float4*>(O)[(size_t)gr * 32 + (c0 >> 2) + 0] = o0;
                reinterpret_cast<float4*>(O)[(size_t)gr * 32 + (c0 >> 2) + 1] = o1;
            }
        }
    }
}

// ---------------------------------------------------------------------------
// CSR build
// ---------------------------------------------------------------------------
__global__ __launch_bounds__(256) void count_kernel(
    const int* __restrict__ dst, int* __restrict__ cnt, int E)
{
    int e = blockIdx.x * 256 + threadIdx.x;
    if (e < E) atomicAdd(&cnt[dst[e]], 1);
}

// Single-block exclusive scan over cnt[0..N) -> row_start[0..N], cursor copy.
__global__ __launch_bounds__(1024) void scan_kernel(
    const int* __restrict__ cnt, int* __restrict__ row_start,
    int* __restrict__ cursor, int N)
{
    __shared__ int partial[1024];
    const int tid = threadIdx.x;
    const int per = (N + 1023) / 1024;
    const int base = tid * per;

    int sum = 0;
    for (int i = 0; i < per; ++i) {
        int idx = base + i;
        if (idx < N) sum += cnt[idx];
    }
    partial[tid] = sum;
    __syncthreads();

    for (int off = 1; off < 1024; off <<= 1) {
        int val = 0;
        if (tid >= off) val = partial[tid - off];
        __syncthreads();
        if (tid >= off) partial[tid] += val;
        __syncthreads();
    }

    int excl = (tid == 0) ? 0 : partial[tid - 1];
    for (int i = 0; i < per; ++i) {
        int idx = base + i;
        if (idx < N) {
            row_start[idx] = excl;
            cursor[idx] = excl;
            excl += cnt[idx];
        }
    }
    if (tid == 0) row_start[N] = partial[1023];
}

__global__ __launch_bounds__(256) void scatter_kernel(
    const int* __restrict__ src, const int* __restrict__ dst,
    int* __restrict__ cursor, int* __restrict__ csr_src, int E)
{
    int e = blockIdx.x * 256 + threadIdx.x;
    if (e < E) {
        int d = dst[e];
        int pos = atomicAdd(&cursor[d], 1);
        csr_src[pos] = src[e];
    }
}

// ---------------------------------------------------------------------------
// Fused score+softmax+aggregate. One 64-lane wave per destination node.
// Lane i owns dims i and 64+i. Head of dim i is i>>4 (accA), of 64+i is
// 4+(i>>4) (accB). Softmax normalization deferred: out = (sum ex*v)/(sum ex).
// ---------------------------------------------------------------------------
__global__ __launch_bounds__(256) void fused_agg_kernel(
    const float* __restrict__ q, const float* __restrict__ k,
    const float* __restrict__ v, const int* __restrict__ row_start,
    const int* __restrict__ csr_src, float* __restrict__ rst, int N)
{
    const int lane = threadIdx.x & 63;
    const int node = blockIdx.x * 4 + (threadIdx.x >> 6);
    if (node >= N) return;

    const int beg = row_start[node];
    const int end = row_start[node + 1];

    const size_t qb = (size_t)node * 128;
    const float qa0 = q[qb + lane];
    const float qa1 = q[qb + 64 + lane];

    float acc0 = 0.f, acc1 = 0.f, z0 = 0.f, z1 = 0.f;

    for (int p = beg; p < end; ++p) {
        const int s = csr_src[p];
        const size_t kb = (size_t)s * 128;
        float pA = qa0 * k[kb + lane];
        float pB = qa1 * k[kb + 64 + lane];
        #pragma unroll
        for (int m = 8; m >= 1; m >>= 1) {
            pA += __shfl_xor(pA, m, 64);
            pB += __shfl_xor(pB, m, 64);
        }
        float eA = (pA >= 0.f) ? pA : NEG_SLOPE * pA;
        float eB = (pB >= 0.f) ? pB : NEG_SLOPE * pB;
        eA = __expf(eA);
        eB = __expf(eB);
        z0 += eA;
        z1 += eB;
        acc0 = fmaf(eA, v[kb + lane], acc0);
        acc1 = fmaf(eB, v[kb + 64 + lane], acc1);
    }

    float r0 = rst[qb + lane];
    float r1 = rst[qb + 64 + lane];
    if (end > beg) {
        r0 += acc0 / z0;
        r1 += acc1 / z1;
    }
    rst[qb + lane] = r0;
    rst[qb + 64 + lane] = r1;
}

extern "C" void kernel_launch(void* const* d_in, const int* in_sizes, int n_in,
                              void* d_out, int out_size, void* d_ws, size_t ws_size,
                              hipStream_t stream) {
    const float* h    = (const float*)d_in[0];
    const int*   src  = (const int*)d_in[2];
    const int*   dst  = (const int*)d_in[3];
    const float* Wq   = (const float*)d_in[4];
    const float* Wk   = (const float*)d_in[5];
    const float* Wv   = (const float*)d_in[6];
    const float* Wres = (const float*)d_in[8];
    float* rst = (float*)d_out;

    const int N = in_sizes[0] / 128;   // 50000
    const int E = in_sizes[2];         // 800000

    float* q  = (float*)d_ws;
    float* k  = q + (size_t)N * 128;
    float* v  = k + (size_t)N * 128;
    int* cnt       = (int*)(v + (size_t)N * 128);
    int* row_start = cnt + N;          // N+1 entries
    int* cursor    = row_start + (N + 1);
    int* csr_src   = cursor + N;

    hipMemsetAsync(cnt, 0, (size_t)N * sizeof(int), stream);

    proj4_kernel<<<(N + 63) / 64, 256, 0, stream>>>(h, Wq, Wk, Wv, Wres,
                                                    q, k, v, rst, N);
    count_kernel<<<(E + 255) / 256, 256, 0, stream>>>(dst, cnt, E);
    scan_kernel<<<1, 1024, 0, stream>>>(cnt, row_start, cursor, N);
    scatter_kernel<<<(E + 255) / 256, 256, 0, stream>>>(src, dst, cursor,
                                                        csr_src, E);
    fused_agg_kernel<<<(N + 3) / 4, 256, 0, stream>>>(q, k, v, row_start,
                                                      csr_src, rst, N);
}

// Round 3
// 402.058 us; speedup vs baseline: 1.4975x; 1.2103x over previous
//
#include <hip/hip_runtime.h>

// GAT forward, CSR-fused + bf16-MFMA projections.
// N=50000, E=800000, IN_DIM=128, H=8, D=16.

#define NEG_SLOPE 0.2f

typedef __attribute__((ext_vector_type(8))) short short8;   // 8 bf16 (4 VGPRs)
typedef __attribute__((ext_vector_type(4))) float f32x4;    // MFMA C/D frag

__device__ __forceinline__ unsigned short f2bf(float f) {
    unsigned int u = __builtin_bit_cast(unsigned int, f);
    u = (u + 0x7fffu + ((u >> 16) & 1u)) >> 16;   // RNE
    return (unsigned short)u;
}
__device__ __forceinline__ float bf2f(unsigned short s) {
    unsigned int u = (unsigned int)s << 16;
    return __builtin_bit_cast(float, u);
}

// ---------------------------------------------------------------------------
// Convert h (N*32 float4s) and the 4 weight matrices (4*4096 float4s) to bf16.
// ---------------------------------------------------------------------------
__global__ __launch_bounds__(256) void convert_kernel(
    const float* __restrict__ h,
    const float* __restrict__ Wq, const float* __restrict__ Wk,
    const float* __restrict__ Wv, const float* __restrict__ Wres,
    unsigned short* __restrict__ hbf, unsigned short* __restrict__ wbf,
    int h4, int total4)
{
    const int stride = gridDim.x * 256;
    for (int t = blockIdx.x * 256 + threadIdx.x; t < total4; t += stride) {
        float4 val;
        unsigned short* dst;
        if (t < h4) {
            val = reinterpret_cast<const float4*>(h)[t];
            dst = hbf + (size_t)t * 4;
        } else {
            int u = t - h4;
            int w = u >> 12;            // 4096 float4s per 128x128 matrix
            int rem = u & 4095;
            const float* W = (w == 0) ? Wq : (w == 1) ? Wk : (w == 2) ? Wv : Wres;
            val = reinterpret_cast<const float4*>(W)[rem];
            dst = wbf + (size_t)u * 4;
        }
        ushort4 o;
        o.x = f2bf(val.x); o.y = f2bf(val.y); o.z = f2bf(val.z); o.w = f2bf(val.w);
        *reinterpret_cast<ushort4*>(dst) = o;
    }
}

// ---------------------------------------------------------------------------
// MFMA projections: C = h @ W^T for Wq,Wk,Wv,Wres.
// Block = 256 thr = 4 waves; wave owns 16 node-rows x 128 out-cols x 4 Ws.
// A frag (16x32): lane l holds h[row0 + (l&15)][kk*32 + (l>>4)*8 + t], t=0..7.
// B frag (32x16): lane l holds W[ct*16 + (l&15)][kk*32 + (l>>4)*8 + t]
//   (B[k][o] = W[o][k], so W rows give B columns directly).
// D frag: C[row0 + (l>>4)*4 + j][ct*16 + (l&15)] = acc[j].
// q,res stored fp32; k,v stored bf16 for the aggregation gather.
// ---------------------------------------------------------------------------
__global__ __launch_bounds__(256) void proj_mfma_kernel(
    const unsigned short* __restrict__ hbf,
    const unsigned short* __restrict__ wbf,
    float* __restrict__ q, unsigned short* __restrict__ kb,
    unsigned short* __restrict__ vb, float* __restrict__ res, int N)
{
    const int wid = threadIdx.x >> 6;
    const int lane = threadIdx.x & 63;
    const int row0 = blockIdx.x * 64 + wid * 16;
    const int r = lane & 15, g = lane >> 4;

    int arow = row0 + r;
    if (arow >= N) arow = N - 1;          // clamp; duplicate rows, stores guarded
    const unsigned short* hrow = hbf + (size_t)arow * 128 + g * 8;
    short8 afrag[4];
    #pragma unroll
    for (int kk = 0; kk < 4; ++kk)
        afrag[kk] = *reinterpret_cast<const short8*>(hrow + kk * 32);

    for (int w = 0; w < 4; ++w) {
        const unsigned short* wb = wbf + w * 16384 + (size_t)r * 128 + g * 8;
        f32x4 acc[8];
        #pragma unroll
        for (int ct = 0; ct < 8; ++ct) acc[ct] = (f32x4)(0.f);

        #pragma unroll
        for (int ct = 0; ct < 8; ++ct) {
            #pragma unroll
            for (int kk = 0; kk < 4; ++kk) {
                short8 bfrag = *reinterpret_cast<const short8*>(wb + ct * 16 * 128 + kk * 32);
                acc[ct] = __builtin_amdgcn_mfma_f32_16x16x32_bf16(
                    afrag[kk], bfrag, acc[ct], 0, 0, 0);
            }
        }

        #pragma unroll
        for (int j = 0; j < 4; ++j) {
            int orow = row0 + g * 4 + j;
            if (orow < N) {
                if (w == 0) {
                    #pragma unroll
                    for (int ct = 0; ct < 8; ++ct)
                        q[(size_t)orow * 128 + ct * 16 + r] = acc[ct][j];
                } else if (w == 3) {
                    #pragma unroll
                    for (int ct = 0; ct < 8; ++ct)
                        res[(size_t)orow * 128 + ct * 16 + r] = acc[ct][j];
                } else {
                    unsigned short* O = (w == 1) ? kb : vb;
                    #pragma unroll
                    for (int ct = 0; ct < 8; ++ct)
                        O[(size_t)orow * 128 + ct * 16 + r] = f2bf(acc[ct][j]);
                }
            }
        }
    }
}

// ---------------------------------------------------------------------------
// CSR build
// ---------------------------------------------------------------------------
__global__ __launch_bounds__(256) void count_kernel(
    const int* __restrict__ dst, int* __restrict__ cnt, int E)
{
    int e = blockIdx.x * 256 + threadIdx.x;
    if (e < E) atomicAdd(&cnt[dst[e]], 1);
}

__global__ __launch_bounds__(1024) void scan_kernel(
    const int* __restrict__ cnt, int* __restrict__ row_start,
    int* __restrict__ cursor, int N)
{
    __shared__ int partial[1024];
    const int tid = threadIdx.x;
    const int per = (N + 1023) / 1024;
    const int base = tid * per;

    int sum = 0;
    for (int i = 0; i < per; ++i) {
        int idx = base + i;
        if (idx < N) sum += cnt[idx];
    }
    partial[tid] = sum;
    __syncthreads();

    for (int off = 1; off < 1024; off <<= 1) {
        int val = 0;
        if (tid >= off) val = partial[tid - off];
        __syncthreads();
        if (tid >= off) partial[tid] += val;
        __syncthreads();
    }

    int excl = (tid == 0) ? 0 : partial[tid - 1];
    for (int i = 0; i < per; ++i) {
        int idx = base + i;
        if (idx < N) {
            row_start[idx] = excl;
            cursor[idx] = excl;
            excl += cnt[idx];
        }
    }
    if (tid == 0) row_start[N] = partial[1023];
}

__global__ __launch_bounds__(256) void scatter_kernel(
    const int* __restrict__ src, const int* __restrict__ dst,
    int* __restrict__ cursor, int* __restrict__ csr_src, int E)
{
    int e = blockIdx.x * 256 + threadIdx.x;
    if (e < E) {
        int d = dst[e];
        int pos = atomicAdd(&cursor[d], 1);
        csr_src[pos] = src[e];
    }
}

// ---------------------------------------------------------------------------
// Fused score+softmax+aggregate. One wave per destination node.
// Lane i owns dims 2i,2i+1 (head = i>>3). Per edge: wave reads the full
// 256B bf16 k row and v row coalesced; 8-lane shfl_xor dot reduce; exp;
// register accumulation. Normalize once at the end.
// ---------------------------------------------------------------------------
__global__ __launch_bounds__(256) void fused_agg_kernel(
    const float* __restrict__ q, const unsigned short* __restrict__ kb,
    const unsigned short* __restrict__ vb, const int* __restrict__ row_start,
    const int* __restrict__ csr_src, float* __restrict__ rst, int N)
{
    const int lane = threadIdx.x & 63;
    const int node = blockIdx.x * 4 + (threadIdx.x >> 6);
    if (node >= N) return;

    const int beg = row_start[node];
    const int end = row_start[node + 1];

    const size_t base = (size_t)node * 128 + 2 * lane;
    const float2 qv = *reinterpret_cast<const float2*>(q + base - 0);

    float acc0 = 0.f, acc1 = 0.f, z = 0.f;

    for (int p = beg; p < end; ++p) {
        const int s = csr_src[p];
        const size_t off = (size_t)s * 128 + 2 * lane;
        ushort2 kraw = *reinterpret_cast<const ushort2*>(kb + off);
        ushort2 vraw = *reinterpret_cast<const ushort2*>(vb + off);
        float pA = qv.x * bf2f(kraw.x) + qv.y * bf2f(kraw.y);
        #pragma unroll
        for (int m = 4; m >= 1; m >>= 1)
            pA += __shfl_xor(pA, m, 64);
        float e = (pA >= 0.f) ? pA : NEG_SLOPE * pA;
        e = __expf(e);
        z += e;
        acc0 = fmaf(e, bf2f(vraw.x), acc0);
        acc1 = fmaf(e, bf2f(vraw.y), acc1);
    }

    float2 rv = *reinterpret_cast<const float2*>(rst + base);
    if (end > beg) {
        float inv = 1.f / z;
        rv.x = fmaf(acc0, inv, rv.x);
        rv.y = fmaf(acc1, inv, rv.y);
    }
    *reinterpret_cast<float2*>(rst + base) = rv;
}

extern "C" void kernel_launch(void* const* d_in, const int* in_sizes, int n_in,
                              void* d_out, int out_size, void* d_ws, size_t ws_size,
                              hipStream_t stream) {
    const float* h    = (const float*)d_in[0];
    const int*   src  = (const int*)d_in[2];
    const int*   dst  = (const int*)d_in[3];
    const float* Wq   = (const float*)d_in[4];
    const float* Wk   = (const float*)d_in[5];
    const float* Wv   = (const float*)d_in[6];
    const float* Wres = (const float*)d_in[8];
    float* rst = (float*)d_out;

    const int N = in_sizes[0] / 128;   // 50000
    const int E = in_sizes[2];         // 800000

    float*          q   = (float*)d_ws;
    unsigned short* hbf = (unsigned short*)(q + (size_t)N * 128);
    unsigned short* kb  = hbf + (size_t)N * 128;
    unsigned short* vb  = kb + (size_t)N * 128;
    unsigned short* wbf = vb + (size_t)N * 128;
    int* cnt       = (int*)(wbf + 4 * 16384);
    int* row_start = cnt + N;
    int* cursor    = row_start + (N + 1);
    int* csr_src   = cursor + N;

    const int h4 = N * 32;
    const int total4 = h4 + 4 * 4096;

    hipMemsetAsync(cnt, 0, (size_t)N * sizeof(int), stream);

    convert_kernel<<<2048, 256, 0, stream>>>(h, Wq, Wk, Wv, Wres, hbf, wbf,
                                             h4, total4);
    proj_mfma_kernel<<<(N + 63) / 64, 256, 0, stream>>>(hbf, wbf, q, kb, vb,
                                                        rst, N);
    count_kernel<<<(E + 255) / 256, 256, 0, stream>>>(dst, cnt, E);
    scan_kernel<<<1, 1024, 0, stream>>>(cnt, row_start, cursor, N);
    scatter_kernel<<<(E + 255) / 256, 256, 0, stream>>>(src, dst, cursor,
                                                        csr_src, E);
    fused_agg_kernel<<<(N + 3) / 4, 256, 0, stream>>>(q, kb, vb, row_start,
                                                      csr_src, rst, N);
}

// Round 4
// 280.238 us; speedup vs baseline: 2.1485x; 1.4347x over previous
//
#include <hip/hip_runtime.h>

// GAT forward, CSR-fused + bf16-MFMA projections + parallel scan.
// N=50000, E=800000, IN_DIM=128, H=8, D=16.

#define NEG_SLOPE 0.2f

typedef __attribute__((ext_vector_type(8))) short short8;   // 8 bf16 (4 VGPRs)
typedef __attribute__((ext_vector_type(4))) float f32x4;    // MFMA C/D frag

__device__ __forceinline__ unsigned short f2bf(float f) {
    unsigned int u = __builtin_bit_cast(unsigned int, f);
    u = (u + 0x7fffu + ((u >> 16) & 1u)) >> 16;   // RNE
    return (unsigned short)u;
}
__device__ __forceinline__ float bf2f(unsigned short s) {
    unsigned int u = (unsigned int)s << 16;
    return __builtin_bit_cast(float, u);
}

// ---------------------------------------------------------------------------
// Convert h and the 4 weight matrices to bf16.
// ---------------------------------------------------------------------------
__global__ __launch_bounds__(256) void convert_kernel(
    const float* __restrict__ h,
    const float* __restrict__ Wq, const float* __restrict__ Wk,
    const float* __restrict__ Wv, const float* __restrict__ Wres,
    unsigned short* __restrict__ hbf, unsigned short* __restrict__ wbf,
    int h4, int total4)
{
    const int stride = gridDim.x * 256;
    for (int t = blockIdx.x * 256 + threadIdx.x; t < total4; t += stride) {
        float4 val;
        unsigned short* dst;
        if (t < h4) {
            val = reinterpret_cast<const float4*>(h)[t];
            dst = hbf + (size_t)t * 4;
        } else {
            int u = t - h4;
            int w = u >> 12;
            int rem = u & 4095;
            const float* W = (w == 0) ? Wq : (w == 1) ? Wk : (w == 2) ? Wv : Wres;
            val = reinterpret_cast<const float4*>(W)[rem];
            dst = wbf + (size_t)u * 4;
        }
        ushort4 o;
        o.x = f2bf(val.x); o.y = f2bf(val.y); o.z = f2bf(val.z); o.w = f2bf(val.w);
        *reinterpret_cast<ushort4*>(dst) = o;
    }
}

// ---------------------------------------------------------------------------
// MFMA projections (unchanged from round 2).
// ---------------------------------------------------------------------------
__global__ __launch_bounds__(256) void proj_mfma_kernel(
    const unsigned short* __restrict__ hbf,
    const unsigned short* __restrict__ wbf,
    float* __restrict__ q, unsigned short* __restrict__ kb,
    unsigned short* __restrict__ vb, float* __restrict__ res, int N)
{
    const int wid = threadIdx.x >> 6;
    const int lane = threadIdx.x & 63;
    const int row0 = blockIdx.x * 64 + wid * 16;
    const int r = lane & 15, g = lane >> 4;

    int arow = row0 + r;
    if (arow >= N) arow = N - 1;
    const unsigned short* hrow = hbf + (size_t)arow * 128 + g * 8;
    short8 afrag[4];
    #pragma unroll
    for (int kk = 0; kk < 4; ++kk)
        afrag[kk] = *reinterpret_cast<const short8*>(hrow + kk * 32);

    for (int w = 0; w < 4; ++w) {
        const unsigned short* wb = wbf + w * 16384 + (size_t)r * 128 + g * 8;
        f32x4 acc[8];
        #pragma unroll
        for (int ct = 0; ct < 8; ++ct) acc[ct] = (f32x4)(0.f);

        #pragma unroll
        for (int ct = 0; ct < 8; ++ct) {
            #pragma unroll
            for (int kk = 0; kk < 4; ++kk) {
                short8 bfrag = *reinterpret_cast<const short8*>(wb + ct * 16 * 128 + kk * 32);
                acc[ct] = __builtin_amdgcn_mfma_f32_16x16x32_bf16(
                    afrag[kk], bfrag, acc[ct], 0, 0, 0);
            }
        }

        #pragma unroll
        for (int j = 0; j < 4; ++j) {
            int orow = row0 + g * 4 + j;
            if (orow < N) {
                if (w == 0) {
                    #pragma unroll
                    for (int ct = 0; ct < 8; ++ct)
                        q[(size_t)orow * 128 + ct * 16 + r] = acc[ct][j];
                } else if (w == 3) {
                    #pragma unroll
                    for (int ct = 0; ct < 8; ++ct)
                        res[(size_t)orow * 128 + ct * 16 + r] = acc[ct][j];
                } else {
                    unsigned short* O = (w == 1) ? kb : vb;
                    #pragma unroll
                    for (int ct = 0; ct < 8; ++ct)
                        O[(size_t)orow * 128 + ct * 16 + r] = f2bf(acc[ct][j]);
                }
            }
        }
    }
}

// ---------------------------------------------------------------------------
// CSR build: count -> 3-phase parallel scan -> scatter.
// ---------------------------------------------------------------------------
__global__ __launch_bounds__(256) void count_kernel(
    const int* __restrict__ dst, int* __restrict__ cnt, int E)
{
    int e = blockIdx.x * 256 + threadIdx.x;
    if (e < E) atomicAdd(&cnt[dst[e]], 1);
}

// Phase 1: per-block (1024-elem) sums. Grid = ceil(N/1024) blocks.
__global__ __launch_bounds__(256) void blocksum_kernel(
    const int* __restrict__ cnt, int* __restrict__ bsum, int N)
{
    __shared__ int ws[4];
    const int tid = threadIdx.x;
    int base = blockIdx.x * 1024 + tid * 4;
    int s = 0;
    if (base + 3 < N) {
        int4 v = *reinterpret_cast<const int4*>(cnt + base);
        s = v.x + v.y + v.z + v.w;
    } else {
        for (int i = 0; i < 4; ++i)
            if (base + i < N) s += cnt[base + i];
    }
    #pragma unroll
    for (int m = 32; m >= 1; m >>= 1) s += __shfl_xor(s, m, 64);
    if ((tid & 63) == 0) ws[tid >> 6] = s;
    __syncthreads();
    if (tid == 0) bsum[blockIdx.x] = ws[0] + ws[1] + ws[2] + ws[3];
}

// Phase 2: exclusive-scan the block sums in one wave (NB <= 64).
__global__ __launch_bounds__(64) void scanbsum_kernel(
    int* __restrict__ bsum, int NB)
{
    int lane = threadIdx.x;
    int v = (lane < NB) ? bsum[lane] : 0;
    #pragma unroll
    for (int off = 1; off < 64; off <<= 1) {
        int t = __shfl_up(v, off, 64);
        if (lane >= off) v += t;
    }
    int ex = __shfl_up(v, 1, 64);
    if (lane == 0) ex = 0;
    if (lane < NB) bsum[lane] = ex;
}

// Phase 3: block-local exclusive scan + block offset -> row_start, cursor.
__global__ __launch_bounds__(256) void scanfinal_kernel(
    const int* __restrict__ cnt, const int* __restrict__ boff,
    int* __restrict__ row_start, int* __restrict__ cursor, int N, int E)
{
    __shared__ int wsum[4];
    const int tid = threadIdx.x, lane = tid & 63, w = tid >> 6;
    int base = blockIdx.x * 1024 + tid * 4;
    int a0 = 0, a1 = 0, a2 = 0, a3 = 0;
    if (base + 3 < N) {
        int4 v = *reinterpret_cast<const int4*>(cnt + base);
        a0 = v.x; a1 = v.y; a2 = v.z; a3 = v.w;
    } else {
        if (base + 0 < N) a0 = cnt[base + 0];
        if (base + 1 < N) a1 = cnt[base + 1];
        if (base + 2 < N) a2 = cnt[base + 2];
        if (base + 3 < N) a3 = cnt[base + 3];
    }
    const int tsum = a0 + a1 + a2 + a3;
    int v = tsum;
    #pragma unroll
    for (int off = 1; off < 64; off <<= 1) {
        int t = __shfl_up(v, off, 64);
        if (lane >= off) v += t;
    }
    if (lane == 63) wsum[w] = v;
    __syncthreads();
    int woff = 0;
    for (int i = 0; i < w; ++i) woff += wsum[i];
    int run = boff[blockIdx.x] + woff + v - tsum;   // thread-exclusive prefix

    int r0 = run, r1 = run + a0, r2 = r1 + a1, r3 = r2 + a2;
    if (base + 3 < N) {
        int4 o = make_int4(r0, r1, r2, r3);
        *reinterpret_cast<int4*>(row_start + base) = o;
        *reinterpret_cast<int4*>(cursor + base) = o;
    } else {
        int rr[4] = {r0, r1, r2, r3};
        for (int i = 0; i < 4; ++i)
            if (base + i < N) { row_start[base + i] = rr[i]; cursor[base + i] = rr[i]; }
    }
    if (blockIdx.x == 0 && tid == 0) row_start[N] = E;
}

__global__ __launch_bounds__(256) void scatter_kernel(
    const int* __restrict__ src, const int* __restrict__ dst,
    int* __restrict__ cursor, int* __restrict__ csr_src, int E)
{
    int e = blockIdx.x * 256 + threadIdx.x;
    if (e < E) {
        int d = dst[e];
        int pos = atomicAdd(&cursor[d], 1);
        csr_src[pos] = src[e];
    }
}

// ---------------------------------------------------------------------------
// Fused score+softmax+aggregate (unchanged from round 2).
// ---------------------------------------------------------------------------
__global__ __launch_bounds__(256) void fused_agg_kernel(
    const float* __restrict__ q, const unsigned short* __restrict__ kb,
    const unsigned short* __restrict__ vb, const int* __restrict__ row_start,
    const int* __restrict__ csr_src, float* __restrict__ rst, int N)
{
    const int lane = threadIdx.x & 63;
    const int node = blockIdx.x * 4 + (threadIdx.x >> 6);
    if (node >= N) return;

    const int beg = row_start[node];
    const int end = row_start[node + 1];

    const size_t base = (size_t)node * 128 + 2 * lane;
    const float2 qv = *reinterpret_cast<const float2*>(q + base);

    float acc0 = 0.f, acc1 = 0.f, z = 0.f;

    for (int p = beg; p < end; ++p) {
        const int s = csr_src[p];
        const size_t off = (size_t)s * 128 + 2 * lane;
        ushort2 kraw = *reinterpret_cast<const ushort2*>(kb + off);
        ushort2 vraw = *reinterpret_cast<const ushort2*>(vb + off);
        float pA = qv.x * bf2f(kraw.x) + qv.y * bf2f(kraw.y);
        #pragma unroll
        for (int m = 4; m >= 1; m >>= 1)
            pA += __shfl_xor(pA, m, 64);
        float e = (pA >= 0.f) ? pA : NEG_SLOPE * pA;
        e = __expf(e);
        z += e;
        acc0 = fmaf(e, bf2f(vraw.x), acc0);
        acc1 = fmaf(e, bf2f(vraw.y), acc1);
    }

    float2 rv = *reinterpret_cast<const float2*>(rst + base);
    if (end > beg) {
        float inv = 1.f / z;
        rv.x = fmaf(acc0, inv, rv.x);
        rv.y = fmaf(acc1, inv, rv.y);
    }
    *reinterpret_cast<float2*>(rst + base) = rv;
}

extern "C" void kernel_launch(void* const* d_in, const int* in_sizes, int n_in,
                              void* d_out, int out_size, void* d_ws, size_t ws_size,
                              hipStream_t stream) {
    const float* h    = (const float*)d_in[0];
    const int*   src  = (const int*)d_in[2];
    const int*   dst  = (const int*)d_in[3];
    const float* Wq   = (const float*)d_in[4];
    const float* Wk   = (const float*)d_in[5];
    const float* Wv   = (const float*)d_in[6];
    const float* Wres = (const float*)d_in[8];
    float* rst = (float*)d_out;

    const int N = in_sizes[0] / 128;   // 50000
    const int E = in_sizes[2];         // 800000

    float*          q   = (float*)d_ws;
    unsigned short* hbf = (unsigned short*)(q + (size_t)N * 128);
    unsigned short* kb  = hbf + (size_t)N * 128;
    unsigned short* vb  = kb + (size_t)N * 128;
    unsigned short* wbf = vb + (size_t)N * 128;
    int* cnt       = (int*)(wbf + 4 * 16384);
    int* row_start = cnt + N;          // N+1
    int* cursor    = row_start + (N + 1);
    int* csr_src   = cursor + N;
    int* bsum      = csr_src + E;

    const int h4 = N * 32;
    const int total4 = h4 + 4 * 4096;
    const int NB = (N + 1023) / 1024;  // 49 <= 64

    hipMemsetAsync(cnt, 0, (size_t)N * sizeof(int), stream);

    convert_kernel<<<2048, 256, 0, stream>>>(h, Wq, Wk, Wv, Wres, hbf, wbf,
                                             h4, total4);
    proj_mfma_kernel<<<(N + 63) / 64, 256, 0, stream>>>(hbf, wbf, q, kb, vb,
                                                        rst, N);
    count_kernel<<<(E + 255) / 256, 256, 0, stream>>>(dst, cnt, E);
    blocksum_kernel<<<NB, 256, 0, stream>>>(cnt, bsum, N);
    scanbsum_kernel<<<1, 64, 0, stream>>>(bsum, NB);
    scanfinal_kernel<<<NB, 256, 0, stream>>>(cnt, bsum, row_start, cursor, N, E);
    scatter_kernel<<<(E + 255) / 256, 256, 0, stream>>>(src, dst, cursor,
                                                        csr_src, E);
    fused_agg_kernel<<<(N + 3) / 4, 256, 0, stream>>>(q, kb, vb, row_start,
                                                      csr_src, rst, N);
}

// Round 5
// 276.047 us; speedup vs baseline: 2.1812x; 1.0152x over previous
//
#include <hip/hip_runtime.h>

// GAT forward: bf16-MFMA projections (fp32 h read + in-reg convert),
// CSR build with parallel scan, fused score+softmax+aggregate.
// N=50000, E=800000, IN_DIM=128, H=8, D=16.

#define NEG_SLOPE 0.2f

typedef __attribute__((ext_vector_type(8))) short short8;   // 8 bf16 (4 VGPRs)
typedef __attribute__((ext_vector_type(4))) float f32x4;    // MFMA C/D frag

__device__ __forceinline__ unsigned short f2bf(float f) {
    unsigned int u = __builtin_bit_cast(unsigned int, f);
    u = (u + 0x7fffu + ((u >> 16) & 1u)) >> 16;   // RNE
    return (unsigned short)u;
}
__device__ __forceinline__ float bf2f(unsigned short s) {
    unsigned int u = (unsigned int)s << 16;
    return __builtin_bit_cast(float, u);
}

// ---------------------------------------------------------------------------
// Zero the cnt array (replaces hipMemsetAsync, whose graph-captured fill
// node measured ~116 us). N ints = N/4 int4s.
// ---------------------------------------------------------------------------
__global__ __launch_bounds__(256) void zero_kernel(int* __restrict__ p, int n4)
{
    int t = blockIdx.x * 256 + threadIdx.x;
    if (t < n4) reinterpret_cast<int4*>(p)[t] = make_int4(0, 0, 0, 0);
}

// ---------------------------------------------------------------------------
// Convert the 4 weight matrices to bf16 (tiny: 16384 float4s).
// ---------------------------------------------------------------------------
__global__ __launch_bounds__(256) void wconv_kernel(
    const float* __restrict__ Wq, const float* __restrict__ Wk,
    const float* __restrict__ Wv, const float* __restrict__ Wres,
    unsigned short* __restrict__ wbf)
{
    int t = blockIdx.x * 256 + threadIdx.x;   // < 16384
    int w = t >> 12;
    int rem = t & 4095;
    const float* W = (w == 0) ? Wq : (w == 1) ? Wk : (w == 2) ? Wv : Wres;
    float4 val = reinterpret_cast<const float4*>(W)[rem];
    ushort4 o;
    o.x = f2bf(val.x); o.y = f2bf(val.y); o.z = f2bf(val.z); o.w = f2bf(val.w);
    reinterpret_cast<ushort4*>(wbf)[t] = o;
}

// ---------------------------------------------------------------------------
// MFMA projections: C = h @ W^T for Wq,Wk,Wv,Wres.
// Block = 4 waves; wave owns 16 node-rows x 128 out-cols x all 4 Ws.
// A frag built from fp32 h with in-register RNE bf16 convert.
// q,res stored fp32; k,v stored bf16 for the aggregation gather.
// ---------------------------------------------------------------------------
__global__ __launch_bounds__(256) void proj_mfma_kernel(
    const float* __restrict__ h,
    const unsigned short* __restrict__ wbf,
    float* __restrict__ q, unsigned short* __restrict__ kb,
    unsigned short* __restrict__ vb, float* __restrict__ res, int N)
{
    const int wid = threadIdx.x >> 6;
    const int lane = threadIdx.x & 63;
    const int row0 = blockIdx.x * 64 + wid * 16;
    const int r = lane & 15, g = lane >> 4;

    int arow = row0 + r;
    if (arow >= N) arow = N - 1;          // clamp; stores guarded below
    const float* hrow = h + (size_t)arow * 128 + g * 8;
    short8 afrag[4];
    #pragma unroll
    for (int kk = 0; kk < 4; ++kk) {
        float4 lo = *reinterpret_cast<const float4*>(hrow + kk * 32);
        float4 hi = *reinterpret_cast<const float4*>(hrow + kk * 32 + 4);
        short8 a;
        a[0] = (short)f2bf(lo.x); a[1] = (short)f2bf(lo.y);
        a[2] = (short)f2bf(lo.z); a[3] = (short)f2bf(lo.w);
        a[4] = (short)f2bf(hi.x); a[5] = (short)f2bf(hi.y);
        a[6] = (short)f2bf(hi.z); a[7] = (short)f2bf(hi.w);
        afrag[kk] = a;
    }

    for (int w = 0; w < 4; ++w) {
        const unsigned short* wb = wbf + w * 16384 + (size_t)r * 128 + g * 8;
        f32x4 acc[8];
        #pragma unroll
        for (int ct = 0; ct < 8; ++ct) acc[ct] = (f32x4)(0.f);

        #pragma unroll
        for (int ct = 0; ct < 8; ++ct) {
            #pragma unroll
            for (int kk = 0; kk < 4; ++kk) {
                short8 bfrag = *reinterpret_cast<const short8*>(wb + ct * 16 * 128 + kk * 32);
                acc[ct] = __builtin_amdgcn_mfma_f32_16x16x32_bf16(
                    afrag[kk], bfrag, acc[ct], 0, 0, 0);
            }
        }

        #pragma unroll
        for (int j = 0; j < 4; ++j) {
            int orow = row0 + g * 4 + j;
            if (orow < N) {
                if (w == 0) {
                    #pragma unroll
                    for (int ct = 0; ct < 8; ++ct)
                        q[(size_t)orow * 128 + ct * 16 + r] = acc[ct][j];
                } else if (w == 3) {
                    #pragma unroll
                    for (int ct = 0; ct < 8; ++ct)
                        res[(size_t)orow * 128 + ct * 16 + r] = acc[ct][j];
                } else {
                    unsigned short* O = (w == 1) ? kb : vb;
                    #pragma unroll
                    for (int ct = 0; ct < 8; ++ct)
                        O[(size_t)orow * 128 + ct * 16 + r] = f2bf(acc[ct][j]);
                }
            }
        }
    }
}

// ---------------------------------------------------------------------------
// CSR build: count -> 3-phase parallel scan -> scatter.
// ---------------------------------------------------------------------------
__global__ __launch_bounds__(256) void count_kernel(
    const int* __restrict__ dst, int* __restrict__ cnt, int E)
{
    int e = blockIdx.x * 256 + threadIdx.x;
    if (e < E) atomicAdd(&cnt[dst[e]], 1);
}

// Phase 1: per-block (1024-elem) sums.
__global__ __launch_bounds__(256) void blocksum_kernel(
    const int* __restrict__ cnt, int* __restrict__ bsum, int N)
{
    __shared__ int ws[4];
    const int tid = threadIdx.x;
    int base = blockIdx.x * 1024 + tid * 4;
    int s = 0;
    if (base + 3 < N) {
        int4 v = *reinterpret_cast<const int4*>(cnt + base);
        s = v.x + v.y + v.z + v.w;
    } else {
        for (int i = 0; i < 4; ++i)
            if (base + i < N) s += cnt[base + i];
    }
    #pragma unroll
    for (int m = 32; m >= 1; m >>= 1) s += __shfl_xor(s, m, 64);
    if ((tid & 63) == 0) ws[tid >> 6] = s;
    __syncthreads();
    if (tid == 0) bsum[blockIdx.x] = ws[0] + ws[1] + ws[2] + ws[3];
}

// Phase 2: exclusive-scan the block sums in one wave (NB <= 64).
__global__ __launch_bounds__(64) void scanbsum_kernel(
    int* __restrict__ bsum, int NB)
{
    int lane = threadIdx.x;
    int v = (lane < NB) ? bsum[lane] : 0;
    #pragma unroll
    for (int off = 1; off < 64; off <<= 1) {
        int t = __shfl_up(v, off, 64);
        if (lane >= off) v += t;
    }
    int ex = __shfl_up(v, 1, 64);
    if (lane == 0) ex = 0;
    if (lane < NB) bsum[lane] = ex;
}

// Phase 3: block-local exclusive scan + block offset -> row_start, cursor.
__global__ __launch_bounds__(256) void scanfinal_kernel(
    const int* __restrict__ cnt, const int* __restrict__ boff,
    int* __restrict__ row_start, int* __restrict__ cursor, int N, int E)
{
    __shared__ int wsum[4];
    const int tid = threadIdx.x, lane = tid & 63, w = tid >> 6;
    int base = blockIdx.x * 1024 + tid * 4;
    int a0 = 0, a1 = 0, a2 = 0, a3 = 0;
    if (base + 3 < N) {
        int4 v = *reinterpret_cast<const int4*>(cnt + base);
        a0 = v.x; a1 = v.y; a2 = v.z; a3 = v.w;
    } else {
        if (base + 0 < N) a0 = cnt[base + 0];
        if (base + 1 < N) a1 = cnt[base + 1];
        if (base + 2 < N) a2 = cnt[base + 2];
        if (base + 3 < N) a3 = cnt[base + 3];
    }
    const int tsum = a0 + a1 + a2 + a3;
    int v = tsum;
    #pragma unroll
    for (int off = 1; off < 64; off <<= 1) {
        int t = __shfl_up(v, off, 64);
        if (lane >= off) v += t;
    }
    if (lane == 63) wsum[w] = v;
    __syncthreads();
    int woff = 0;
    for (int i = 0; i < w; ++i) woff += wsum[i];
    int run = boff[blockIdx.x] + woff + v - tsum;   // thread-exclusive prefix

    int r0 = run, r1 = run + a0, r2 = r1 + a1, r3 = r2 + a2;
    if (base + 3 < N) {
        int4 o = make_int4(r0, r1, r2, r3);
        *reinterpret_cast<int4*>(row_start + base) = o;
        *reinterpret_cast<int4*>(cursor + base) = o;
    } else {
        int rr[4] = {r0, r1, r2, r3};
        for (int i = 0; i < 4; ++i)
            if (base + i < N) { row_start[base + i] = rr[i]; cursor[base + i] = rr[i]; }
    }
    if (blockIdx.x == 0 && tid == 0) row_start[N] = E;
}

__global__ __launch_bounds__(256) void scatter_kernel(
    const int* __restrict__ src, const int* __restrict__ dst,
    int* __restrict__ cursor, int* __restrict__ csr_src, int E)
{
    int e = blockIdx.x * 256 + threadIdx.x;
    if (e < E) {
        int d = dst[e];
        int pos = atomicAdd(&cursor[d], 1);
        csr_src[pos] = src[e];
    }
}

// ---------------------------------------------------------------------------
// Fused score+softmax+aggregate. One wave per destination node.
// Lane i owns dims 2i,2i+1 (head = i>>3). Softmax normalization deferred.
// ---------------------------------------------------------------------------
__global__ __launch_bounds__(256) void fused_agg_kernel(
    const float* __restrict__ q, const unsigned short* __restrict__ kb,
    const unsigned short* __restrict__ vb, const int* __restrict__ row_start,
    const int* __restrict__ csr_src, float* __restrict__ rst, int N)
{
    const int lane = threadIdx.x & 63;
    const int node = blockIdx.x * 4 + (threadIdx.x >> 6);
    if (node >= N) return;

    const int beg = row_start[node];
    const int end = row_start[node + 1];

    const size_t base = (size_t)node * 128 + 2 * lane;
    const float2 qv = *reinterpret_cast<const float2*>(q + base);

    float acc0 = 0.f, acc1 = 0.f, z = 0.f;

    for (int p = beg; p < end; ++p) {
        const int s = csr_src[p];
        const size_t off = (size_t)s * 128 + 2 * lane;
        ushort2 kraw = *reinterpret_cast<const ushort2*>(kb + off);
        ushort2 vraw = *reinterpret_cast<const ushort2*>(vb + off);
        float pA = qv.x * bf2f(kraw.x) + qv.y * bf2f(kraw.y);
        #pragma unroll
        for (int m = 4; m >= 1; m >>= 1)
            pA += __shfl_xor(pA, m, 64);
        float e = (pA >= 0.f) ? pA : NEG_SLOPE * pA;
        e = __expf(e);
        z += e;
        acc0 = fmaf(e, bf2f(vraw.x), acc0);
        acc1 = fmaf(e, bf2f(vraw.y), acc1);
    }

    float2 rv = *reinterpret_cast<const float2*>(rst + base);
    if (end > beg) {
        float inv = 1.f / z;
        rv.x = fmaf(acc0, inv, rv.x);
        rv.y = fmaf(acc1, inv, rv.y);
    }
    *reinterpret_cast<float2*>(rst + base) = rv;
}

extern "C" void kernel_launch(void* const* d_in, const int* in_sizes, int n_in,
                              void* d_out, int out_size, void* d_ws, size_t ws_size,
                              hipStream_t stream) {
    const float* h    = (const float*)d_in[0];
    const int*   src  = (const int*)d_in[2];
    const int*   dst  = (const int*)d_in[3];
    const float* Wq   = (const float*)d_in[4];
    const float* Wk   = (const float*)d_in[5];
    const float* Wv   = (const float*)d_in[6];
    const float* Wres = (const float*)d_in[8];
    float* rst = (float*)d_out;

    const int N = in_sizes[0] / 128;   // 50000
    const int E = in_sizes[2];         // 800000

    float*          q   = (float*)d_ws;
    unsigned short* kb  = (unsigned short*)(q + (size_t)N * 128);
    unsigned short* vb  = kb + (size_t)N * 128;
    unsigned short* wbf = vb + (size_t)N * 128;
    int* cnt       = (int*)(wbf + 4 * 16384);
    int* row_start = cnt + N;          // N+1
    int* cursor    = row_start + (N + 1);
    int* csr_src   = cursor + N;
    int* bsum      = csr_src + E;

    const int NB = (N + 1023) / 1024;  // 49 <= 64

    zero_kernel<<<(N / 4 + 255) / 256, 256, 0, stream>>>(cnt, N / 4);
    wconv_kernel<<<64, 256, 0, stream>>>(Wq, Wk, Wv, Wres, wbf);
    proj_mfma_kernel<<<(N + 63) / 64, 256, 0, stream>>>(h, wbf, q, kb, vb,
                                                        rst, N);
    count_kernel<<<(E + 255) / 256, 256, 0, stream>>>(dst, cnt, E);
    blocksum_kernel<<<NB, 256, 0, stream>>>(cnt, bsum, N);
    scanbsum_kernel<<<1, 64, 0, stream>>>(bsum, NB);
    scanfinal_kernel<<<NB, 256, 0, stream>>>(cnt, bsum, row_start, cursor, N, E);
    scatter_kernel<<<(E + 255) / 256, 256, 0, stream>>>(src, dst, cursor,
                                                        csr_src, E);
    fused_agg_kernel<<<(N + 3) / 4, 256, 0, stream>>>(q, kb, vb, row_start,
                                                      csr_src, rst, N);
}

// Round 6
// 197.637 us; speedup vs baseline: 3.0465x; 1.3967x over previous
//
#include <hip/hip_runtime.h>

// GAT forward: bf16-MFMA projections (packed-fragment weights, 32 rows/wave),
// CSR build with parallel scan, fused score+softmax+aggregate (unroll-2).
// N=50000, E=800000, IN_DIM=128, H=8, D=16.

#define NEG_SLOPE 0.2f

typedef __attribute__((ext_vector_type(8))) short short8;   // 8 bf16 (4 VGPRs)
typedef __attribute__((ext_vector_type(4))) float f32x4;    // MFMA C/D frag

__device__ __forceinline__ unsigned short f2bf(float f) {
    unsigned int u = __builtin_bit_cast(unsigned int, f);
    u = (u + 0x7fffu + ((u >> 16) & 1u)) >> 16;   // RNE
    return (unsigned short)u;
}
__device__ __forceinline__ float bf2f(unsigned short s) {
    unsigned int u = (unsigned int)s << 16;
    return __builtin_bit_cast(float, u);
}

// ---------------------------------------------------------------------------
// Zero the cnt array.
// ---------------------------------------------------------------------------
__global__ __launch_bounds__(256) void zero_kernel(int* __restrict__ p, int n4)
{
    int t = blockIdx.x * 256 + threadIdx.x;
    if (t < n4) reinterpret_cast<int4*>(p)[t] = make_int4(0, 0, 0, 0);
}

// ---------------------------------------------------------------------------
// Pack the 4 weight matrices into MFMA-B-fragment-linear bf16 layout:
//   wpk[(((w*8+ct)*4+kk)*64 + lane)*8 + t] = W_w[ct*16+(lane&15)][kk*32+(lane>>4)*8+t]
// so the proj kernel's B loads are perfectly lane-coalesced (1KB per instr).
// 8192 threads, one short8 each.
// ---------------------------------------------------------------------------
__global__ __launch_bounds__(256) void wconv_kernel(
    const float* __restrict__ Wq, const float* __restrict__ Wk,
    const float* __restrict__ Wv, const float* __restrict__ Wres,
    unsigned short* __restrict__ wpk)
{
    int u = blockIdx.x * 256 + threadIdx.x;   // < 8192
    int l = u & 63;
    int v = u >> 6;          // (w*8+ct)*4+kk
    int kk = v & 3;
    int wct = v >> 2;        // w*8+ct
    int ct = wct & 7;
    int w = wct >> 3;
    const float* W = (w == 0) ? Wq : (w == 1) ? Wk : (w == 2) ? Wv : Wres;
    const float* srcp = W + (size_t)(ct * 16 + (l & 15)) * 128 + kk * 32 + (l >> 4) * 8;
    float4 lo = *reinterpret_cast<const float4*>(srcp);
    float4 hi = *reinterpret_cast<const float4*>(srcp + 4);
    short8 o;
    o[0] = (short)f2bf(lo.x); o[1] = (short)f2bf(lo.y);
    o[2] = (short)f2bf(lo.z); o[3] = (short)f2bf(lo.w);
    o[4] = (short)f2bf(hi.x); o[5] = (short)f2bf(hi.y);
    o[6] = (short)f2bf(hi.z); o[7] = (short)f2bf(hi.w);
    *reinterpret_cast<short8*>(wpk + (size_t)u * 8) = o;
}

// ---------------------------------------------------------------------------
// MFMA projections: C = h @ W^T for Wq,Wk,Wv,Wres.
// Block = 4 waves; each wave owns 32 node-rows (two 16-row groups) so every
// packed B fragment is loaded once and used twice.
// q,res stored fp32; k,v stored bf16 for the aggregation gather.
// ---------------------------------------------------------------------------
__global__ __launch_bounds__(256) void proj_mfma_kernel(
    const float* __restrict__ h,
    const unsigned short* __restrict__ wpk,
    float* __restrict__ q, unsigned short* __restrict__ kb,
    unsigned short* __restrict__ vb, float* __restrict__ res, int N)
{
    const int wid = threadIdx.x >> 6;
    const int lane = threadIdx.x & 63;
    const int row0 = blockIdx.x * 128 + wid * 32;   // first of 32 rows
    const int r = lane & 15, g = lane >> 4;

    // A fragments for both 16-row groups, fp32 h -> bf16 in-register
    short8 afrag[2][4];
    #pragma unroll
    for (int grp = 0; grp < 2; ++grp) {
        int arow = row0 + grp * 16 + r;
        if (arow >= N) arow = N - 1;        // clamp; stores guarded below
        const float* hrow = h + (size_t)arow * 128 + g * 8;
        #pragma unroll
        for (int kk = 0; kk < 4; ++kk) {
            float4 lo = *reinterpret_cast<const float4*>(hrow + kk * 32);
            float4 hi = *reinterpret_cast<const float4*>(hrow + kk * 32 + 4);
            short8 a;
            a[0] = (short)f2bf(lo.x); a[1] = (short)f2bf(lo.y);
            a[2] = (short)f2bf(lo.z); a[3] = (short)f2bf(lo.w);
            a[4] = (short)f2bf(hi.x); a[5] = (short)f2bf(hi.y);
            a[6] = (short)f2bf(hi.z); a[7] = (short)f2bf(hi.w);
            afrag[grp][kk] = a;
        }
    }

    for (int w = 0; w < 4; ++w) {
        f32x4 acc[2][8];
        #pragma unroll
        for (int grp = 0; grp < 2; ++grp)
            #pragma unroll
            for (int ct = 0; ct < 8; ++ct) acc[grp][ct] = (f32x4)(0.f);

        #pragma unroll
        for (int ct = 0; ct < 8; ++ct) {
            // coalesced packed B loads: consecutive lanes -> consecutive 16B
            const unsigned short* bp =
                wpk + ((size_t)((w * 8 + ct) * 4) * 64 + lane) * 8;
            short8 bfrag[4];
            #pragma unroll
            for (int kk = 0; kk < 4; ++kk)
                bfrag[kk] = *reinterpret_cast<const short8*>(bp + (size_t)kk * 512);
            #pragma unroll
            for (int grp = 0; grp < 2; ++grp)
                #pragma unroll
                for (int kk = 0; kk < 4; ++kk)
                    acc[grp][ct] = __builtin_amdgcn_mfma_f32_16x16x32_bf16(
                        afrag[grp][kk], bfrag[kk], acc[grp][ct], 0, 0, 0);
        }

        #pragma unroll
        for (int grp = 0; grp < 2; ++grp) {
            #pragma unroll
            for (int j = 0; j < 4; ++j) {
                int orow = row0 + grp * 16 + g * 4 + j;
                if (orow < N) {
                    if (w == 0) {
                        #pragma unroll
                        for (int ct = 0; ct < 8; ++ct)
                            q[(size_t)orow * 128 + ct * 16 + r] = acc[grp][ct][j];
                    } else if (w == 3) {
                        #pragma unroll
                        for (int ct = 0; ct < 8; ++ct)
                            res[(size_t)orow * 128 + ct * 16 + r] = acc[grp][ct][j];
                    } else {
                        unsigned short* O = (w == 1) ? kb : vb;
                        #pragma unroll
                        for (int ct = 0; ct < 8; ++ct)
                            O[(size_t)orow * 128 + ct * 16 + r] = f2bf(acc[grp][ct][j]);
                    }
                }
            }
        }
    }
}

// ---------------------------------------------------------------------------
// CSR build: count -> 3-phase parallel scan -> scatter.
// ---------------------------------------------------------------------------
__global__ __launch_bounds__(256) void count_kernel(
    const int* __restrict__ dst, int* __restrict__ cnt, int E)
{
    int e = blockIdx.x * 256 + threadIdx.x;
    if (e < E) atomicAdd(&cnt[dst[e]], 1);
}

__global__ __launch_bounds__(256) void blocksum_kernel(
    const int* __restrict__ cnt, int* __restrict__ bsum, int N)
{
    __shared__ int ws[4];
    const int tid = threadIdx.x;
    int base = blockIdx.x * 1024 + tid * 4;
    int s = 0;
    if (base + 3 < N) {
        int4 v = *reinterpret_cast<const int4*>(cnt + base);
        s = v.x + v.y + v.z + v.w;
    } else {
        for (int i = 0; i < 4; ++i)
            if (base + i < N) s += cnt[base + i];
    }
    #pragma unroll
    for (int m = 32; m >= 1; m >>= 1) s += __shfl_xor(s, m, 64);
    if ((tid & 63) == 0) ws[tid >> 6] = s;
    __syncthreads();
    if (tid == 0) bsum[blockIdx.x] = ws[0] + ws[1] + ws[2] + ws[3];
}

__global__ __launch_bounds__(64) void scanbsum_kernel(
    int* __restrict__ bsum, int NB)
{
    int lane = threadIdx.x;
    int v = (lane < NB) ? bsum[lane] : 0;
    #pragma unroll
    for (int off = 1; off < 64; off <<= 1) {
        int t = __shfl_up(v, off, 64);
        if (lane >= off) v += t;
    }
    int ex = __shfl_up(v, 1, 64);
    if (lane == 0) ex = 0;
    if (lane < NB) bsum[lane] = ex;
}

__global__ __launch_bounds__(256) void scanfinal_kernel(
    const int* __restrict__ cnt, const int* __restrict__ boff,
    int* __restrict__ row_start, int* __restrict__ cursor, int N, int E)
{
    __shared__ int wsum[4];
    const int tid = threadIdx.x, lane = tid & 63, w = tid >> 6;
    int base = blockIdx.x * 1024 + tid * 4;
    int a0 = 0, a1 = 0, a2 = 0, a3 = 0;
    if (base + 3 < N) {
        int4 v = *reinterpret_cast<const int4*>(cnt + base);
        a0 = v.x; a1 = v.y; a2 = v.z; a3 = v.w;
    } else {
        if (base + 0 < N) a0 = cnt[base + 0];
        if (base + 1 < N) a1 = cnt[base + 1];
        if (base + 2 < N) a2 = cnt[base + 2];
        if (base + 3 < N) a3 = cnt[base + 3];
    }
    const int tsum = a0 + a1 + a2 + a3;
    int v = tsum;
    #pragma unroll
    for (int off = 1; off < 64; off <<= 1) {
        int t = __shfl_up(v, off, 64);
        if (lane >= off) v += t;
    }
    if (lane == 63) wsum[w] = v;
    __syncthreads();
    int woff = 0;
    for (int i = 0; i < w; ++i) woff += wsum[i];
    int run = boff[blockIdx.x] + woff + v - tsum;

    int r0 = run, r1 = run + a0, r2 = r1 + a1, r3 = r2 + a2;
    if (base + 3 < N) {
        int4 o = make_int4(r0, r1, r2, r3);
        *reinterpret_cast<int4*>(row_start + base) = o;
        *reinterpret_cast<int4*>(cursor + base) = o;
    } else {
        int rr[4] = {r0, r1, r2, r3};
        for (int i = 0; i < 4; ++i)
            if (base + i < N) { row_start[base + i] = rr[i]; cursor[base + i] = rr[i]; }
    }
    if (blockIdx.x == 0 && tid == 0) row_start[N] = E;
}

__global__ __launch_bounds__(256) void scatter_kernel(
    const int* __restrict__ src, const int* __restrict__ dst,
    int* __restrict__ cursor, int* __restrict__ csr_src, int E)
{
    int e = blockIdx.x * 256 + threadIdx.x;
    if (e < E) {
        int d = dst[e];
        int pos = atomicAdd(&cursor[d], 1);
        csr_src[pos] = src[e];
    }
}

// ---------------------------------------------------------------------------
// Fused score+softmax+aggregate. One wave per destination node, unroll-2:
// both edges' k/v loads are issued before either shfl-reduce chain, so the
// two L2/L3 latency chains overlap.
// ---------------------------------------------------------------------------
__global__ __launch_bounds__(256) void fused_agg_kernel(
    const float* __restrict__ q, const unsigned short* __restrict__ kb,
    const unsigned short* __restrict__ vb, const int* __restrict__ row_start,
    const int* __restrict__ csr_src, float* __restrict__ rst, int N)
{
    const int lane = threadIdx.x & 63;
    const int node = blockIdx.x * 4 + (threadIdx.x >> 6);
    if (node >= N) return;

    const int beg = row_start[node];
    const int end = row_start[node + 1];

    const size_t base = (size_t)node * 128 + 2 * lane;
    const float2 qv = *reinterpret_cast<const float2*>(q + base);

    float acc0 = 0.f, acc1 = 0.f, z = 0.f;

    int p = beg;
    if ((end - beg) & 1) {
        const int s = csr_src[p++];
        const size_t off = (size_t)s * 128 + 2 * lane;
        ushort2 kraw = *reinterpret_cast<const ushort2*>(kb + off);
        ushort2 vraw = *reinterpret_cast<const ushort2*>(vb + off);
        float pA = qv.x * bf2f(kraw.x) + qv.y * bf2f(kraw.y);
        #pragma unroll
        for (int m = 4; m >= 1; m >>= 1) pA += __shfl_xor(pA, m, 64);
        float e = (pA >= 0.f) ? pA : NEG_SLOPE * pA;
        e = __expf(e);
        z += e;
        acc0 = fmaf(e, bf2f(vraw.x), acc0);
        acc1 = fmaf(e, bf2f(vraw.y), acc1);
    }

    for (; p < end; p += 2) {
        const int s0 = csr_src[p];
        const int s1 = csr_src[p + 1];
        const size_t o0 = (size_t)s0 * 128 + 2 * lane;
        const size_t o1 = (size_t)s1 * 128 + 2 * lane;
        ushort2 k0 = *reinterpret_cast<const ushort2*>(kb + o0);
        ushort2 v0 = *reinterpret_cast<const ushort2*>(vb + o0);
        ushort2 k1 = *reinterpret_cast<const ushort2*>(kb + o1);
        ushort2 v1 = *reinterpret_cast<const ushort2*>(vb + o1);
        float pA = qv.x * bf2f(k0.x) + qv.y * bf2f(k0.y);
        float pB = qv.x * bf2f(k1.x) + qv.y * bf2f(k1.y);
        #pragma unroll
        for (int m = 4; m >= 1; m >>= 1) {
            pA += __shfl_xor(pA, m, 64);
            pB += __shfl_xor(pB, m, 64);
        }
        float e0 = (pA >= 0.f) ? pA : NEG_SLOPE * pA;
        float e1 = (pB >= 0.f) ? pB : NEG_SLOPE * pB;
        e0 = __expf(e0);
        e1 = __expf(e1);
        z += e0 + e1;
        acc0 = fmaf(e0, bf2f(v0.x), acc0);
        acc1 = fmaf(e0, bf2f(v0.y), acc1);
        acc0 = fmaf(e1, bf2f(v1.x), acc0);
        acc1 = fmaf(e1, bf2f(v1.y), acc1);
    }

    float2 rv = *reinterpret_cast<const float2*>(rst + base);
    if (end > beg) {
        float inv = 1.f / z;
        rv.x = fmaf(acc0, inv, rv.x);
        rv.y = fmaf(acc1, inv, rv.y);
    }
    *reinterpret_cast<float2*>(rst + base) = rv;
}

extern "C" void kernel_launch(void* const* d_in, const int* in_sizes, int n_in,
                              void* d_out, int out_size, void* d_ws, size_t ws_size,
                              hipStream_t stream) {
    const float* h    = (const float*)d_in[0];
    const int*   src  = (const int*)d_in[2];
    const int*   dst  = (const int*)d_in[3];
    const float* Wq   = (const float*)d_in[4];
    const float* Wk   = (const float*)d_in[5];
    const float* Wv   = (const float*)d_in[6];
    const float* Wres = (const float*)d_in[8];
    float* rst = (float*)d_out;

    const int N = in_sizes[0] / 128;   // 50000
    const int E = in_sizes[2];         // 800000

    float*          q   = (float*)d_ws;
    unsigned short* kb  = (unsigned short*)(q + (size_t)N * 128);
    unsigned short* vb  = kb + (size_t)N * 128;
    unsigned short* wpk = vb + (size_t)N * 128;
    int* cnt       = (int*)(wpk + 4 * 16384);
    int* row_start = cnt + N;          // N+1
    int* cursor    = row_start + (N + 1);
    int* csr_src   = cursor + N;
    int* bsum      = csr_src + E;

    const int NB = (N + 1023) / 1024;  // 49 <= 64

    zero_kernel<<<(N / 4 + 255) / 256, 256, 0, stream>>>(cnt, N / 4);
    wconv_kernel<<<32, 256, 0, stream>>>(Wq, Wk, Wv, Wres, wpk);
    proj_mfma_kernel<<<(N + 127) / 128, 256, 0, stream>>>(h, wpk, q, kb, vb,
                                                          rst, N);
    count_kernel<<<(E + 255) / 256, 256, 0, stream>>>(dst, cnt, E);
    blocksum_kernel<<<NB, 256, 0, stream>>>(cnt, bsum, N);
    scanbsum_kernel<<<1, 64, 0, stream>>>(bsum, NB);
    scanfinal_kernel<<<NB, 256, 0, stream>>>(cnt, bsum, row_start, cursor, N, E);
    scatter_kernel<<<(E + 255) / 256, 256, 0, stream>>>(src, dst, cursor,
                                                        csr_src, E);
    fused_agg_kernel<<<(N + 3) / 4, 256, 0, stream>>>(q, kb, vb, row_start,
                                                      csr_src, rst, N);
}

// Round 7
// 170.062 us; speedup vs baseline: 3.5405x; 1.1621x over previous
//
#include <hip/hip_runtime.h>

// GAT forward: bf16-MFMA projections fused with edge-count, CSR scan,
// scatter, fused score+softmax+aggregate with interleaved kv gather.
// N=50000, E=800000, IN_DIM=128, H=8, D=16.

#define NEG_SLOPE 0.2f
#define CB 1024   // count-role blocks fused into proj kernel

typedef __attribute__((ext_vector_type(8))) short short8;   // 8 bf16
typedef __attribute__((ext_vector_type(4))) float f32x4;    // MFMA C/D frag

__device__ __forceinline__ unsigned short f2bf(float f) {
    unsigned int u = __builtin_bit_cast(unsigned int, f);
    u = (u + 0x7fffu + ((u >> 16) & 1u)) >> 16;   // RNE
    return (unsigned short)u;
}
__device__ __forceinline__ float bf2f(unsigned short s) {
    unsigned int u = (unsigned int)s << 16;
    return __builtin_bit_cast(float, u);
}

// ---------------------------------------------------------------------------
// Kernel 1: zero cnt + pack weights to MFMA-fragment-linear bf16.
//   wpk[(((w*8+ct)*4+kk)*64 + lane)*8 + t]
//     = W_w[ct*16+(lane&15)][kk*32+(lane>>4)*8+t]
// ---------------------------------------------------------------------------
__global__ __launch_bounds__(256) void zero_wconv_kernel(
    const float* __restrict__ Wq, const float* __restrict__ Wk,
    const float* __restrict__ Wv, const float* __restrict__ Wres,
    unsigned short* __restrict__ wpk, int* __restrict__ cnt, int n4)
{
    int t = blockIdx.x * 256 + threadIdx.x;
    if (t < 8192) {
        int l = t & 63;
        int v = t >> 6;
        int kk = v & 3;
        int wct = v >> 2;
        int ct = wct & 7;
        int w = wct >> 3;
        const float* W = (w == 0) ? Wq : (w == 1) ? Wk : (w == 2) ? Wv : Wres;
        const float* srcp = W + (size_t)(ct * 16 + (l & 15)) * 128 + kk * 32 + (l >> 4) * 8;
        float4 lo = *reinterpret_cast<const float4*>(srcp);
        float4 hi = *reinterpret_cast<const float4*>(srcp + 4);
        short8 o;
        o[0] = (short)f2bf(lo.x); o[1] = (short)f2bf(lo.y);
        o[2] = (short)f2bf(lo.z); o[3] = (short)f2bf(lo.w);
        o[4] = (short)f2bf(hi.x); o[5] = (short)f2bf(hi.y);
        o[6] = (short)f2bf(hi.z); o[7] = (short)f2bf(hi.w);
        *reinterpret_cast<short8*>(wpk + (size_t)t * 8) = o;
    } else {
        int u = t - 8192;
        if (u < n4) reinterpret_cast<int4*>(cnt)[u] = make_int4(0, 0, 0, 0);
    }
}

// ---------------------------------------------------------------------------
// Kernel 2: MFMA projections + fused edge-count.
// Blocks [0,PB): proj — 4 waves, each owns 32 node-rows x 128 cols x 4 Ws.
// Blocks [PB,PB+CB): count — grid-stride histogram of dst into cnt.
// Outputs: q bf16 [N][128]; kv interleaved bf16 [N][256]
//   (kv[n][4p+0..3] = {k[2p],k[2p+1],v[2p],v[2p+1]}); res fp32 -> d_out.
// ---------------------------------------------------------------------------
__global__ __launch_bounds__(256) void proj_count_kernel(
    const float* __restrict__ h,
    const unsigned short* __restrict__ wpk,
    unsigned short* __restrict__ qb, unsigned short* __restrict__ kvb,
    float* __restrict__ res,
    const int* __restrict__ dst, int* __restrict__ cnt,
    int N, int E, int PB)
{
    if (blockIdx.x >= PB) {
        // ---- count role ----
        int start = (blockIdx.x - PB) * 256 + threadIdx.x;
        for (int e = start; e < E; e += CB * 256)
            atomicAdd(&cnt[dst[e]], 1);
        return;
    }

    const int wid = threadIdx.x >> 6;
    const int lane = threadIdx.x & 63;
    const int row0 = blockIdx.x * 128 + wid * 32;
    const int r = lane & 15, g = lane >> 4;

    short8 afrag[2][4];
    #pragma unroll
    for (int grp = 0; grp < 2; ++grp) {
        int arow = row0 + grp * 16 + r;
        if (arow >= N) arow = N - 1;
        const float* hrow = h + (size_t)arow * 128 + g * 8;
        #pragma unroll
        for (int kk = 0; kk < 4; ++kk) {
            float4 lo = *reinterpret_cast<const float4*>(hrow + kk * 32);
            float4 hi = *reinterpret_cast<const float4*>(hrow + kk * 32 + 4);
            short8 a;
            a[0] = (short)f2bf(lo.x); a[1] = (short)f2bf(lo.y);
            a[2] = (short)f2bf(lo.z); a[3] = (short)f2bf(lo.w);
            a[4] = (short)f2bf(hi.x); a[5] = (short)f2bf(hi.y);
            a[6] = (short)f2bf(hi.z); a[7] = (short)f2bf(hi.w);
            afrag[grp][kk] = a;
        }
    }

    for (int w = 0; w < 4; ++w) {
        f32x4 acc[2][8];
        #pragma unroll
        for (int grp = 0; grp < 2; ++grp)
            #pragma unroll
            for (int ct = 0; ct < 8; ++ct) acc[grp][ct] = (f32x4)(0.f);

        #pragma unroll
        for (int ct = 0; ct < 8; ++ct) {
            const unsigned short* bp =
                wpk + ((size_t)((w * 8 + ct) * 4) * 64 + lane) * 8;
            short8 bfrag[4];
            #pragma unroll
            for (int kk = 0; kk < 4; ++kk)
                bfrag[kk] = *reinterpret_cast<const short8*>(bp + (size_t)kk * 512);
            #pragma unroll
            for (int grp = 0; grp < 2; ++grp)
                #pragma unroll
                for (int kk = 0; kk < 4; ++kk)
                    acc[grp][ct] = __builtin_amdgcn_mfma_f32_16x16x32_bf16(
                        afrag[grp][kk], bfrag[kk], acc[grp][ct], 0, 0, 0);
        }

        #pragma unroll
        for (int grp = 0; grp < 2; ++grp) {
            #pragma unroll
            for (int j = 0; j < 4; ++j) {
                int orow = row0 + grp * 16 + g * 4 + j;
                if (orow < N) {
                    if (w == 0) {
                        #pragma unroll
                        for (int ct = 0; ct < 8; ++ct)
                            qb[(size_t)orow * 128 + ct * 16 + r] = f2bf(acc[grp][ct][j]);
                    } else if (w == 3) {
                        #pragma unroll
                        for (int ct = 0; ct < 8; ++ct)
                            res[(size_t)orow * 128 + ct * 16 + r] = acc[grp][ct][j];
                    } else {
                        // kv interleave: col d -> 4*(d>>1) + (d&1) (+2 for v)
                        const int voff = (w == 2) ? 2 : 0;
                        #pragma unroll
                        for (int ct = 0; ct < 8; ++ct) {
                            int idx = ct * 32 + 4 * (r >> 1) + (r & 1) + voff;
                            kvb[(size_t)orow * 256 + idx] = f2bf(acc[grp][ct][j]);
                        }
                    }
                }
            }
        }
    }
}

// ---------------------------------------------------------------------------
// CSR scan: blocksum -> scanfinal (inline 49-element bsum prefix).
// ---------------------------------------------------------------------------
__global__ __launch_bounds__(256) void blocksum_kernel(
    const int* __restrict__ cnt, int* __restrict__ bsum, int N)
{
    __shared__ int ws[4];
    const int tid = threadIdx.x;
    int base = blockIdx.x * 1024 + tid * 4;
    int s = 0;
    if (base + 3 < N) {
        int4 v = *reinterpret_cast<const int4*>(cnt + base);
        s = v.x + v.y + v.z + v.w;
    } else {
        for (int i = 0; i < 4; ++i)
            if (base + i < N) s += cnt[base + i];
    }
    #pragma unroll
    for (int m = 32; m >= 1; m >>= 1) s += __shfl_xor(s, m, 64);
    if ((tid & 63) == 0) ws[tid >> 6] = s;
    __syncthreads();
    if (tid == 0) bsum[blockIdx.x] = ws[0] + ws[1] + ws[2] + ws[3];
}

__global__ __launch_bounds__(256) void scanfinal_kernel(
    const int* __restrict__ cnt, const int* __restrict__ bsum,
    int* __restrict__ row_start, int* __restrict__ cursor,
    int N, int E, int NB)
{
    __shared__ int sboff;
    __shared__ int wsum[4];
    const int tid = threadIdx.x, lane = tid & 63, w = tid >> 6;

    if (tid < 64) {
        int v = (tid < NB && tid < blockIdx.x) ? bsum[tid] : 0;
        #pragma unroll
        for (int m = 32; m >= 1; m >>= 1) v += __shfl_xor(v, m, 64);
        if (tid == 0) sboff = v;
    }
    __syncthreads();

    int base = blockIdx.x * 1024 + tid * 4;
    int a0 = 0, a1 = 0, a2 = 0, a3 = 0;
    if (base + 3 < N) {
        int4 v = *reinterpret_cast<const int4*>(cnt + base);
        a0 = v.x; a1 = v.y; a2 = v.z; a3 = v.w;
    } else {
        if (base + 0 < N) a0 = cnt[base + 0];
        if (base + 1 < N) a1 = cnt[base + 1];
        if (base + 2 < N) a2 = cnt[base + 2];
        if (base + 3 < N) a3 = cnt[base + 3];
    }
    const int tsum = a0 + a1 + a2 + a3;
    int v = tsum;
    #pragma unroll
    for (int off = 1; off < 64; off <<= 1) {
        int t = __shfl_up(v, off, 64);
        if (lane >= off) v += t;
    }
    if (lane == 63) wsum[w] = v;
    __syncthreads();
    int woff = 0;
    for (int i = 0; i < w; ++i) woff += wsum[i];
    int run = sboff + woff + v - tsum;

    int r0 = run, r1 = run + a0, r2 = r1 + a1, r3 = r2 + a2;
    if (base + 3 < N) {
        int4 o = make_int4(r0, r1, r2, r3);
        *reinterpret_cast<int4*>(row_start + base) = o;
        *reinterpret_cast<int4*>(cursor + base) = o;
    } else {
        int rr[4] = {r0, r1, r2, r3};
        for (int i = 0; i < 4; ++i)
            if (base + i < N) { row_start[base + i] = rr[i]; cursor[base + i] = rr[i]; }
    }
    if (blockIdx.x == 0 && tid == 0) row_start[N] = E;
}

__global__ __launch_bounds__(256) void scatter_kernel(
    const int* __restrict__ src, const int* __restrict__ dst,
    int* __restrict__ cursor, int* __restrict__ csr_src, int E)
{
    int e = blockIdx.x * 256 + threadIdx.x;
    if (e < E) {
        int d = dst[e];
        int pos = atomicAdd(&cursor[d], 1);
        csr_src[pos] = src[e];
    }
}

// ---------------------------------------------------------------------------
// Fused score+softmax+aggregate. One wave per node. Lane i owns dims
// 2i,2i+1 (head = i>>3). Per edge ONE ushort4 load gives {k2i,k2i+1,v2i,v2i+1}.
// Unroll-2 with one-pair-ahead csr index prefetch.
// ---------------------------------------------------------------------------
__global__ __launch_bounds__(256) void fused_agg_kernel(
    const unsigned short* __restrict__ qb,
    const unsigned short* __restrict__ kvb,
    const int* __restrict__ row_start, const int* __restrict__ csr_src,
    float* __restrict__ rst, int N)
{
    const int lane = threadIdx.x & 63;
    const int node = blockIdx.x * 4 + (threadIdx.x >> 6);
    if (node >= N) return;

    const int beg = row_start[node];
    const int end = row_start[node + 1];
    const int nE = end - beg;
    const int* cp = csr_src + beg;

    ushort2 qraw = *reinterpret_cast<const ushort2*>(qb + (size_t)node * 128 + 2 * lane);
    const float qx = bf2f(qraw.x), qy = bf2f(qraw.y);

    float acc0 = 0.f, acc1 = 0.f, z = 0.f;

    int i = 0;
    int sa = (nE > 0) ? cp[0] : 0;
    int sb = (nE > 1) ? cp[1] : 0;

    while (i + 2 <= nE) {
        const int s0 = sa, s1 = sb;
        i += 2;
        if (i < nE)     sa = cp[i];
        if (i + 1 < nE) sb = cp[i + 1];

        ushort4 kv0 = *reinterpret_cast<const ushort4*>(kvb + (size_t)s0 * 256 + 4 * lane);
        ushort4 kv1 = *reinterpret_cast<const ushort4*>(kvb + (size_t)s1 * 256 + 4 * lane);

        float pA = qx * bf2f(kv0.x) + qy * bf2f(kv0.y);
        float pB = qx * bf2f(kv1.x) + qy * bf2f(kv1.y);
        #pragma unroll
        for (int m = 4; m >= 1; m >>= 1) {
            pA += __shfl_xor(pA, m, 64);
            pB += __shfl_xor(pB, m, 64);
        }
        float e0 = (pA >= 0.f) ? pA : NEG_SLOPE * pA;
        float e1 = (pB >= 0.f) ? pB : NEG_SLOPE * pB;
        e0 = __expf(e0);
        e1 = __expf(e1);
        z += e0 + e1;
        acc0 = fmaf(e0, bf2f(kv0.z), acc0);
        acc1 = fmaf(e0, bf2f(kv0.w), acc1);
        acc0 = fmaf(e1, bf2f(kv1.z), acc0);
        acc1 = fmaf(e1, bf2f(kv1.w), acc1);
    }
    if (i < nE) {
        ushort4 kv0 = *reinterpret_cast<const ushort4*>(kvb + (size_t)sa * 256 + 4 * lane);
        float pA = qx * bf2f(kv0.x) + qy * bf2f(kv0.y);
        #pragma unroll
        for (int m = 4; m >= 1; m >>= 1) pA += __shfl_xor(pA, m, 64);
        float e0 = (pA >= 0.f) ? pA : NEG_SLOPE * pA;
        e0 = __expf(e0);
        z += e0;
        acc0 = fmaf(e0, bf2f(kv0.z), acc0);
        acc1 = fmaf(e0, bf2f(kv0.w), acc1);
    }

    const size_t base = (size_t)node * 128 + 2 * lane;
    float2 rv = *reinterpret_cast<const float2*>(rst + base);
    if (nE > 0) {
        float inv = 1.f / z;
        rv.x = fmaf(acc0, inv, rv.x);
        rv.y = fmaf(acc1, inv, rv.y);
    }
    *reinterpret_cast<float2*>(rst + base) = rv;
}

extern "C" void kernel_launch(void* const* d_in, const int* in_sizes, int n_in,
                              void* d_out, int out_size, void* d_ws, size_t ws_size,
                              hipStream_t stream) {
    const float* h    = (const float*)d_in[0];
    const int*   src  = (const int*)d_in[2];
    const int*   dst  = (const int*)d_in[3];
    const float* Wq   = (const float*)d_in[4];
    const float* Wk   = (const float*)d_in[5];
    const float* Wv   = (const float*)d_in[6];
    const float* Wres = (const float*)d_in[8];
    float* rst = (float*)d_out;

    const int N = in_sizes[0] / 128;   // 50000
    const int E = in_sizes[2];         // 800000

    unsigned short* qb  = (unsigned short*)d_ws;           // N*128 bf16
    unsigned short* kvb = qb + (size_t)N * 128;            // N*256 bf16
    unsigned short* wpk = kvb + (size_t)N * 256;           // 65536 bf16
    int* cnt       = (int*)(wpk + 4 * 16384);
    int* row_start = cnt + N;          // N+1
    int* cursor    = row_start + (N + 1);
    int* csr_src   = cursor + N;
    int* bsum      = csr_src + E;

    const int n4 = N / 4;              // 12500 (N divisible by 4)
    const int NB = (N + 1023) / 1024;  // 49 <= 64
    const int PB = (N + 127) / 128;    // proj blocks

    zero_wconv_kernel<<<(8192 + n4 + 255) / 256, 256, 0, stream>>>(
        Wq, Wk, Wv, Wres, wpk, cnt, n4);
    proj_count_kernel<<<PB + CB, 256, 0, stream>>>(h, wpk, qb, kvb, rst,
                                                   dst, cnt, N, E, PB);
    blocksum_kernel<<<NB, 256, 0, stream>>>(cnt, bsum, N);
    scanfinal_kernel<<<NB, 256, 0, stream>>>(cnt, bsum, row_start, cursor,
                                             N, E, NB);
    scatter_kernel<<<(E + 255) / 256, 256, 0, stream>>>(src, dst, cursor,
                                                        csr_src, E);
    fused_agg_kernel<<<(N + 3) / 4, 256, 0, stream>>>(qb, kvb, row_start,
                                                      csr_src, rst, N);
}